// Round 1
// baseline (353.040 us; speedup 1.0000x reference)
//
#include <hip/hip_runtime.h>

#define HID 128
#define BM 256
#define NT 512
#define ROWP 136          // padded row stride in halfs (272 B, 16B-aligned)
#define NTILE 32          // 8192 / BM
#define NNET 92
#define NBLK (NNET * NTILE)

typedef _Float16 f16;
typedef _Float16 f16x4 __attribute__((ext_vector_type(4)));
typedef _Float16 f16x8 __attribute__((ext_vector_type(8)));
typedef float f32x4 __attribute__((ext_vector_type(4)));

// variable indices per network: 8 singles, 28 pairs, 56 trips (lexicographic)
__constant__ signed char VARS_C[NNET][3] = {
  {0,-1,-1},{1,-1,-1},{2,-1,-1},{3,-1,-1},{4,-1,-1},{5,-1,-1},{6,-1,-1},{7,-1,-1},
  {0,1,-1},{0,2,-1},{0,3,-1},{0,4,-1},{0,5,-1},{0,6,-1},{0,7,-1},
  {1,2,-1},{1,3,-1},{1,4,-1},{1,5,-1},{1,6,-1},{1,7,-1},
  {2,3,-1},{2,4,-1},{2,5,-1},{2,6,-1},{2,7,-1},
  {3,4,-1},{3,5,-1},{3,6,-1},{3,7,-1},
  {4,5,-1},{4,6,-1},{4,7,-1},
  {5,6,-1},{5,7,-1},
  {6,7,-1},
  {0,1,2},{0,1,3},{0,1,4},{0,1,5},{0,1,6},{0,1,7},
  {0,2,3},{0,2,4},{0,2,5},{0,2,6},{0,2,7},
  {0,3,4},{0,3,5},{0,3,6},{0,3,7},
  {0,4,5},{0,4,6},{0,4,7},
  {0,5,6},{0,5,7},
  {0,6,7},
  {1,2,3},{1,2,4},{1,2,5},{1,2,6},{1,2,7},
  {1,3,4},{1,3,5},{1,3,6},{1,3,7},
  {1,4,5},{1,4,6},{1,4,7},
  {1,5,6},{1,5,7},
  {1,6,7},
  {2,3,4},{2,3,5},{2,3,6},{2,3,7},
  {2,4,5},{2,4,6},{2,4,7},
  {2,5,6},{2,5,7},
  {2,6,7},
  {3,4,5},{3,4,6},{3,4,7},
  {3,5,6},{3,5,7},
  {3,6,7},
  {4,5,6},{4,5,7},
  {4,6,7},
  {5,6,7}
};

// final = -35*f0 + sum_n COEF[n] * g_n   (derived from the HDMR recursion,
// including the reference's f_jj[variable-index] quirk in the trip term)
__constant__ float COEF_C[NNET] = {
  120.f, 15.f, 15.f, -6.f, -6.f, -6.f, -6.f, -6.f,
  -20.f,-20.f,-20.f,-20.f,-20.f,-20.f,-20.f,-20.f,
  1.f,1.f,1.f,1.f,1.f,1.f,1.f,1.f,1.f,1.f,
  1.f,1.f,1.f,1.f,1.f,1.f,1.f,1.f,1.f,1.f,
  1.f,1.f,1.f,1.f,1.f,1.f,1.f,1.f,1.f,1.f,
  1.f,1.f,1.f,1.f,1.f,1.f,1.f,1.f,1.f,1.f,
  1.f,1.f,1.f,1.f,1.f,1.f,1.f,1.f,1.f,1.f,
  1.f,1.f,1.f,1.f,1.f,1.f,1.f,1.f,1.f,1.f,
  1.f,1.f,1.f,1.f,1.f,1.f,1.f,1.f,1.f,1.f,
  1.f,1.f
};

__device__ __forceinline__ float fsigmoid(float v) {
    return __builtin_amdgcn_rcpf(1.0f + __expf(-v));
}

__global__ __launch_bounds__(NT, 2)
void hdmr_fused(const float* __restrict__ x, const float* __restrict__ f0p,
    const float* __restrict__ Wi1, const float* __restrict__ bi1,
    const float* __restrict__ Wh1, const float* __restrict__ bh1,
    const float* __restrict__ Wo1, const float* __restrict__ bo1,
    const float* __restrict__ Wi2, const float* __restrict__ bi2,
    const float* __restrict__ Wh2, const float* __restrict__ bh2,
    const float* __restrict__ Wo2, const float* __restrict__ bo2,
    const float* __restrict__ Wi3, const float* __restrict__ bi3,
    const float* __restrict__ Wh3, const float* __restrict__ bh3,
    const float* __restrict__ Wo3, const float* __restrict__ bo3,
    float* __restrict__ out)
{
    __shared__ __attribute__((aligned(16))) f16 act[BM][ROWP];       // 69.6 KB, in-place per layer
    __shared__ __attribute__((aligned(16))) f16 wlds[2][HID][ROWP];  // 69.6 KB, double-buffered W
    __shared__ float xs[BM][3];
    __shared__ float wout_s[HID];

    const int tid = threadIdx.x;
    const int bid = blockIdx.x;
    // XCD-contiguous swizzle: same-network tiles land on the same XCD -> W stays in its L2
    const int swz = (bid & 7) * (NBLK / 8) + (bid >> 3);
    const int N = swz >> 5;          // network id 0..91
    const int tile = swz & (NTILE - 1);
    const int m0 = tile * BM;

    int din, lidx;
    const float *Wi, *bi, *Wh, *bh, *Wo, *bo;
    if (N < 8)       { lidx = N;      din = 1; Wi=Wi1; bi=bi1; Wh=Wh1; bh=bh1; Wo=Wo1; bo=bo1; }
    else if (N < 36) { lidx = N - 8;  din = 2; Wi=Wi2; bi=bi2; Wh=Wh2; bh=bh2; Wo=Wo2; bo=bo2; }
    else             { lidx = N - 36; din = 3; Wi=Wi3; bi=bi3; Wh=Wh3; bh=bh3; Wo=Wo3; bo=bo3; }
    Wi += (size_t)lidx * HID * din;
    bi += (size_t)lidx * HID;
    Wh += (size_t)lidx * 2 * HID * HID;
    bh += (size_t)lidx * 2 * HID;
    Wo += (size_t)lidx * HID;
    const float bout = bo[lidx];

    const int v0 = VARS_C[N][0], v1 = VARS_C[N][1], v2 = VARS_C[N][2];

    // ---- stage x slice + W_out ----
    for (int e = tid; e < BM; e += NT) {
        const float* xr = x + (size_t)(m0 + e) * 8;
        xs[e][0] = xr[v0];
        if (din > 1) xs[e][1] = xr[v1];
        if (din > 2) xs[e][2] = xr[v2];
    }
    for (int e = tid; e < HID; e += NT) wout_s[e] = Wo[e];
    __syncthreads();

    // ---- input layer (fp32 VALU): act[m][j] = sigmoid(b_in[j] + sum_i x*W_in[j][i]) ----
    {
        const int j = tid & (HID - 1);
        const float w0 = Wi[j * din + 0];
        const float w1 = (din > 1) ? Wi[j * din + 1] : 0.0f;
        const float w2 = (din > 2) ? Wi[j * din + 2] : 0.0f;
        const float bj = bi[j];
        for (int mm = (tid >> 7); mm < BM; mm += NT / HID) {
            float s = bj + xs[mm][0] * w0;
            if (din > 1) s += xs[mm][1] * w1;
            if (din > 2) s += xs[mm][2] * w2;
            act[mm][j] = (f16)fsigmoid(s);
        }
    }
    // ---- stage W_h layer 0 -> wlds[0] ----
    {
        const float4* w4 = (const float4*)Wh;
        for (int e = tid; e < HID * HID / 4; e += NT) {
            float4 v = w4[e];
            f16x4 hv = { (f16)v.x, (f16)v.y, (f16)v.z, (f16)v.w };
            *(f16x4*)&wlds[0][e >> 5][(e << 2) & (HID - 1)] = hv;
        }
    }
    __syncthreads();

    // ---- 2 hidden layers: MFMA 16x16x32 f16, fp32 accum, in-place act update ----
    const int wv = tid >> 6;        // wave 0..7, owns rows [wv*32, wv*32+32)
    const int lane = tid & 63;
    const int lr = lane & 15;
    const int lk = lane >> 4;       // 0..3

    #pragma unroll
    for (int l = 0; l < 2; ++l) {
        if (l == 0) {
            // prefetch layer-1 weights into wlds[1] (overlaps with layer-0 MFMA)
            const float4* w4 = (const float4*)(Wh + HID * HID);
            for (int e = tid; e < HID * HID / 4; e += NT) {
                float4 v = w4[e];
                f16x4 hv = { (f16)v.x, (f16)v.y, (f16)v.z, (f16)v.w };
                *(f16x4*)&wlds[1][e >> 5][(e << 2) & (HID - 1)] = hv;
            }
        }
        const float* bhl = bh + l * HID;

        f32x4 acc[2][8];
        #pragma unroll
        for (int r = 0; r < 2; ++r)
            #pragma unroll
            for (int c = 0; c < 8; ++c) acc[r][c] = (f32x4){0.f, 0.f, 0.f, 0.f};

        #pragma unroll
        for (int kt = 0; kt < 4; ++kt) {
            const int ko = kt * 32 + lk * 8;
            f16x8 a0 = *(const f16x8*)&act[wv * 32 + lr][ko];
            f16x8 a1 = *(const f16x8*)&act[wv * 32 + 16 + lr][ko];
            #pragma unroll
            for (int ct = 0; ct < 8; ++ct) {
                f16x8 bf = *(const f16x8*)&wlds[l][ct * 16 + lr][ko];
                acc[0][ct] = __builtin_amdgcn_mfma_f32_16x16x32_f16(a0, bf, acc[0][ct], 0, 0, 0);
                acc[1][ct] = __builtin_amdgcn_mfma_f32_16x16x32_f16(a1, bf, acc[1][ct], 0, 0, 0);
            }
        }
        // epilogue: bias + sigmoid, write back in place (own rows only -> race-free)
        #pragma unroll
        for (int ct = 0; ct < 8; ++ct) {
            const float bc = bhl[ct * 16 + lr];
            #pragma unroll
            for (int r = 0; r < 2; ++r) {
                #pragma unroll
                for (int i = 0; i < 4; ++i) {
                    // C/D layout: col = lane&15, row = (lane>>4)*4 + reg
                    float vv = fsigmoid(acc[r][ct][i] + bc);
                    act[wv * 32 + r * 16 + lk * 4 + i][ct * 16 + lr] = (f16)vv;
                }
            }
        }
        __syncthreads();
    }

    // ---- output layer + HDMR combine ----
    {
        const int row = tid >> 1;
        const int hh = (tid & 1) << 6;
        float s = 0.0f;
        #pragma unroll
        for (int j = 0; j < 64; j += 8) {
            f16x8 v = *(const f16x8*)&act[row][hh + j];
            #pragma unroll
            for (int k = 0; k < 8; ++k) s += (float)v[k] * wout_s[hh + j + k];
        }
        s += __shfl_xor(s, 1);
        if ((tid & 1) == 0) {
            float y = s + bout;
            float val = COEF_C[N] * y;
            if (N == 0) val -= 35.0f * f0p[0];   // f0 term added exactly once per row
            atomicAdd(&out[m0 + row], val);
        }
    }
}

extern "C" void kernel_launch(void* const* d_in, const int* in_sizes, int n_in,
                              void* d_out, int out_size, void* d_ws, size_t ws_size,
                              hipStream_t stream) {
    const float* x   = (const float*)d_in[0];
    const float* f0  = (const float*)d_in[1];
    const float* Wi1 = (const float*)d_in[2];
    const float* bi1 = (const float*)d_in[3];
    const float* Wh1 = (const float*)d_in[4];
    const float* bh1 = (const float*)d_in[5];
    const float* Wo1 = (const float*)d_in[6];
    const float* bo1 = (const float*)d_in[7];
    const float* Wi2 = (const float*)d_in[8];
    const float* bi2 = (const float*)d_in[9];
    const float* Wh2 = (const float*)d_in[10];
    const float* bh2 = (const float*)d_in[11];
    const float* Wo2 = (const float*)d_in[12];
    const float* bo2 = (const float*)d_in[13];
    const float* Wi3 = (const float*)d_in[14];
    const float* bi3 = (const float*)d_in[15];
    const float* Wh3 = (const float*)d_in[16];
    const float* bh3 = (const float*)d_in[17];
    const float* Wo3 = (const float*)d_in[18];
    const float* bo3 = (const float*)d_in[19];
    float* out = (float*)d_out;

    hipMemsetAsync(out, 0, (size_t)out_size * sizeof(float), stream);
    hipLaunchKernelGGL(hdmr_fused, dim3(NBLK), dim3(NT), 0, stream,
                       x, f0, Wi1, bi1, Wh1, bh1, Wo1, bo1,
                       Wi2, bi2, Wh2, bh2, Wo2, bo2,
                       Wi3, bi3, Wh3, bh3, Wo3, bo3, out);
}

// Round 2
// 338.721 us; speedup vs baseline: 1.0423x; 1.0423x over previous
//
#include <hip/hip_runtime.h>

#define HID 128
#define BM 128
#define NT 512
#define NTILE 64          // 8192 / BM
#define NNET 92
#define NBLK (NNET * NTILE)   // 5888, divisible by 8 -> bijective XCD swizzle

typedef _Float16 f16;
typedef _Float16 f16x2 __attribute__((ext_vector_type(2)));
typedef _Float16 f16x8 __attribute__((ext_vector_type(8)));
typedef float f32x4 __attribute__((ext_vector_type(4)));

// variable indices per network: 8 singles, 28 pairs, 56 trips (lexicographic)
__constant__ signed char VARS_C[NNET][3] = {
  {0,-1,-1},{1,-1,-1},{2,-1,-1},{3,-1,-1},{4,-1,-1},{5,-1,-1},{6,-1,-1},{7,-1,-1},
  {0,1,-1},{0,2,-1},{0,3,-1},{0,4,-1},{0,5,-1},{0,6,-1},{0,7,-1},
  {1,2,-1},{1,3,-1},{1,4,-1},{1,5,-1},{1,6,-1},{1,7,-1},
  {2,3,-1},{2,4,-1},{2,5,-1},{2,6,-1},{2,7,-1},
  {3,4,-1},{3,5,-1},{3,6,-1},{3,7,-1},
  {4,5,-1},{4,6,-1},{4,7,-1},
  {5,6,-1},{5,7,-1},
  {6,7,-1},
  {0,1,2},{0,1,3},{0,1,4},{0,1,5},{0,1,6},{0,1,7},
  {0,2,3},{0,2,4},{0,2,5},{0,2,6},{0,2,7},
  {0,3,4},{0,3,5},{0,3,6},{0,3,7},
  {0,4,5},{0,4,6},{0,4,7},
  {0,5,6},{0,5,7},
  {0,6,7},
  {1,2,3},{1,2,4},{1,2,5},{1,2,6},{1,2,7},
  {1,3,4},{1,3,5},{1,3,6},{1,3,7},
  {1,4,5},{1,4,6},{1,4,7},
  {1,5,6},{1,5,7},
  {1,6,7},
  {2,3,4},{2,3,5},{2,3,6},{2,3,7},
  {2,4,5},{2,4,6},{2,4,7},
  {2,5,6},{2,5,7},
  {2,6,7},
  {3,4,5},{3,4,6},{3,4,7},
  {3,5,6},{3,5,7},
  {3,6,7},
  {4,5,6},{4,5,7},
  {4,6,7},
  {5,6,7}
};

// final = -35*f0 + sum_n COEF[n] * g_n   (derived from the HDMR recursion,
// including the reference's f_jj[variable-index] quirk in the trip term)
__constant__ float COEF_C[NNET] = {
  120.f, 15.f, 15.f, -6.f, -6.f, -6.f, -6.f, -6.f,
  -20.f,-20.f,-20.f,-20.f,-20.f,-20.f,-20.f,-20.f,
  1.f,1.f,1.f,1.f,1.f,1.f,1.f,1.f,1.f,1.f,
  1.f,1.f,1.f,1.f,1.f,1.f,1.f,1.f,1.f,1.f,
  1.f,1.f,1.f,1.f,1.f,1.f,1.f,1.f,1.f,1.f,
  1.f,1.f,1.f,1.f,1.f,1.f,1.f,1.f,1.f,1.f,
  1.f,1.f,1.f,1.f,1.f,1.f,1.f,1.f,1.f,1.f,
  1.f,1.f,1.f,1.f,1.f,1.f,1.f,1.f,1.f,1.f,
  1.f,1.f,1.f,1.f,1.f,1.f,1.f,1.f,1.f,1.f,
  1.f,1.f
};

__device__ __forceinline__ float fsigmoid(float v) {
    return __builtin_amdgcn_rcpf(1.0f + __expf(-v));
}

// XOR-swizzled byte offset into a [row][128] f16 tile (row stride 256 B).
// Spreads the column slot across banks per 8-row stripe; keeps 16B alignment
// for col multiples of 8 (f16x8 reads).
__device__ __forceinline__ int actoff(int row, int colbyte) {
    return row * 256 + (colbyte ^ ((row & 7) << 4));
}

__global__ __launch_bounds__(NT, 4)   // cap VGPR at 128 -> 2 blocks/CU
void hdmr_fused(const float* __restrict__ x, const float* __restrict__ f0p,
    const float* __restrict__ Wi1, const float* __restrict__ bi1,
    const float* __restrict__ Wh1, const float* __restrict__ bh1,
    const float* __restrict__ Wo1, const float* __restrict__ bo1,
    const float* __restrict__ Wi2, const float* __restrict__ bi2,
    const float* __restrict__ Wh2, const float* __restrict__ bh2,
    const float* __restrict__ Wo2, const float* __restrict__ bo2,
    const float* __restrict__ Wi3, const float* __restrict__ bi3,
    const float* __restrict__ Wh3, const float* __restrict__ bh3,
    const float* __restrict__ Wo3, const float* __restrict__ bo3,
    float* __restrict__ out)
{
    __shared__ __attribute__((aligned(16))) char actb[2][BM * HID * 2]; // 2x32KB ping-pong
    __shared__ float xs[BM][3];
    __shared__ float wout_s[HID];

    const int tid = threadIdx.x;
    const int bid = blockIdx.x;
    // bijective XCD-contiguous swizzle (5888 % 8 == 0): same-network tiles
    // stay on one XCD -> that network's weights live in its L2
    const int swz = (bid & 7) * (NBLK / 8) + (bid >> 3);
    const int N = swz >> 6;            // network id 0..91
    const int tile = swz & (NTILE - 1);
    const int m0 = tile * BM;

    int din, lidx;
    const float *Wi, *bi, *Wh, *bh, *Wo, *bo;
    if (N < 8)       { lidx = N;      din = 1; Wi=Wi1; bi=bi1; Wh=Wh1; bh=bh1; Wo=Wo1; bo=bo1; }
    else if (N < 36) { lidx = N - 8;  din = 2; Wi=Wi2; bi=bi2; Wh=Wh2; bh=bh2; Wo=Wo2; bo=bo2; }
    else             { lidx = N - 36; din = 3; Wi=Wi3; bi=bi3; Wh=Wh3; bh=bh3; Wo=Wo3; bo=bo3; }
    Wi += (size_t)lidx * HID * din;
    bi += (size_t)lidx * HID;
    Wh += (size_t)lidx * 2 * HID * HID;
    bh += (size_t)lidx * 2 * HID;
    Wo += (size_t)lidx * HID;
    const float bout = bo[lidx];

    const int v0 = VARS_C[N][0], v1 = VARS_C[N][1], v2 = VARS_C[N][2];

    // ---- stage x slice + W_out ----
    if (tid < BM) {
        const float* xr = x + (size_t)(m0 + tid) * 8;
        xs[tid][0] = xr[v0];
        if (din > 1) xs[tid][1] = xr[v1];
        if (din > 2) xs[tid][2] = xr[v2];
    }
    if (tid >= NT - HID) wout_s[tid - (NT - HID)] = Wo[tid - (NT - HID)];
    __syncthreads();

    // ---- input layer (fp32 VALU), 2 cols/thread -> act0 ----
    {
        const int j = (tid & 63) * 2;
        const float wA0 = Wi[j * din],       wA1 = (din > 1) ? Wi[j * din + 1] : 0.f,
                    wA2 = (din > 2) ? Wi[j * din + 2] : 0.f;
        const float wB0 = Wi[(j+1) * din],   wB1 = (din > 1) ? Wi[(j+1) * din + 1] : 0.f,
                    wB2 = (din > 2) ? Wi[(j+1) * din + 2] : 0.f;
        const float bA = bi[j], bB = bi[j+1];
        for (int mm = (tid >> 6); mm < BM; mm += NT / 64) {
            float x0 = xs[mm][0];
            float sA = bA + x0 * wA0, sB = bB + x0 * wB0;
            if (din > 1) { float x1 = xs[mm][1]; sA += x1 * wA1; sB += x1 * wB1; }
            if (din > 2) { float x2 = xs[mm][2]; sA += x2 * wA2; sB += x2 * wB2; }
            f16x2 hv = { (f16)fsigmoid(sA), (f16)fsigmoid(sB) };
            *(f16x2*)(actb[0] + actoff(mm, j * 2)) = hv;
        }
    }
    __syncthreads();

    // ---- wave decomposition: 8 waves = 2 row-groups x 4 col-groups ----
    const int wv = tid >> 6;
    const int lane = tid & 63;
    const int lr = lane & 15;
    const int lk = lane >> 4;          // 0..3
    const int R0 = (wv >> 2) * 64;     // 64 rows per wave
    const int C0 = (wv & 3) * 32;      // 32 output cols per wave

    // ---- 2 hidden layers: B-fragments in registers (global->cvt), A from LDS ----
    #pragma unroll
    for (int l = 0; l < 2; ++l) {
        const char* src = actb[l & 1];
        char* dst = actb[(l & 1) ^ 1];
        const float* Whl = Wh + l * HID * HID;
        const float* bhl = bh + l * HID;

        // B-fragments: lane lr holds weight row (out-col) C0+ct*16+lr,
        // k-slice kt*32+lk*8 .. +8 (contiguous fp32 in Wh) -> f16x8
        f16x8 bf[2][4];
        #pragma unroll
        for (int ct = 0; ct < 2; ++ct)
            #pragma unroll
            for (int kt = 0; kt < 4; ++kt) {
                const float* wp = Whl + (size_t)(C0 + ct * 16 + lr) * HID + kt * 32 + lk * 8;
                float4 wa = *(const float4*)wp;
                float4 wb = *(const float4*)(wp + 4);
                bf[ct][kt] = (f16x8){ (f16)wa.x,(f16)wa.y,(f16)wa.z,(f16)wa.w,
                                      (f16)wb.x,(f16)wb.y,(f16)wb.z,(f16)wb.w };
            }
        const float bc0 = bhl[C0 + lr];
        const float bc1 = bhl[C0 + 16 + lr];

        f32x4 acc[4][2];
        #pragma unroll
        for (int rf = 0; rf < 4; ++rf)
            #pragma unroll
            for (int ct = 0; ct < 2; ++ct) acc[rf][ct] = (f32x4){0.f,0.f,0.f,0.f};

        #pragma unroll
        for (int kt = 0; kt < 4; ++kt) {
            const int kb = (kt * 32 + lk * 8) * 2;  // byte col offset
            f16x8 a[4];
            #pragma unroll
            for (int rf = 0; rf < 4; ++rf)
                a[rf] = *(const f16x8*)(src + actoff(R0 + rf * 16 + lr, kb));
            #pragma unroll
            for (int rf = 0; rf < 4; ++rf) {
                acc[rf][0] = __builtin_amdgcn_mfma_f32_16x16x32_f16(a[rf], bf[0][kt], acc[rf][0], 0, 0, 0);
                acc[rf][1] = __builtin_amdgcn_mfma_f32_16x16x32_f16(a[rf], bf[1][kt], acc[rf][1], 0, 0, 0);
            }
        }

        // epilogue: bias + sigmoid -> dst (ping-pong: no read/write race)
        #pragma unroll
        for (int ct = 0; ct < 2; ++ct) {
            const float bc = ct ? bc1 : bc0;
            const int col = C0 + ct * 16 + lr;
            #pragma unroll
            for (int rf = 0; rf < 4; ++rf)
                #pragma unroll
                for (int i = 0; i < 4; ++i) {
                    // C/D layout: col = lane&15, row = (lane>>4)*4 + reg
                    float vv = fsigmoid(acc[rf][ct][i] + bc);
                    *(f16*)(dst + actoff(R0 + rf * 16 + lk * 4 + i, col * 2)) = (f16)vv;
                }
        }
        __syncthreads();
    }

    // ---- output layer + HDMR combine (act back in buffer 0) ----
    {
        const int row = tid >> 2;
        const int seg = tid & 3;
        float s = 0.0f;
        #pragma unroll
        for (int jj = 0; jj < 4; ++jj) {
            const int col = seg * 32 + jj * 8;
            f16x8 v = *(const f16x8*)(actb[0] + actoff(row, col * 2));
            #pragma unroll
            for (int k = 0; k < 8; ++k) s += (float)v[k] * wout_s[col + k];
        }
        s += __shfl_xor(s, 1);
        s += __shfl_xor(s, 2);
        if (seg == 0) {
            float y = s + bout;
            float val = COEF_C[N] * y;
            if (N == 0) val -= 35.0f * f0p[0];   // f0 term added exactly once per row
            atomicAdd(&out[m0 + row], val);
        }
    }
}

extern "C" void kernel_launch(void* const* d_in, const int* in_sizes, int n_in,
                              void* d_out, int out_size, void* d_ws, size_t ws_size,
                              hipStream_t stream) {
    const float* x   = (const float*)d_in[0];
    const float* f0  = (const float*)d_in[1];
    const float* Wi1 = (const float*)d_in[2];
    const float* bi1 = (const float*)d_in[3];
    const float* Wh1 = (const float*)d_in[4];
    const float* bh1 = (const float*)d_in[5];
    const float* Wo1 = (const float*)d_in[6];
    const float* bo1 = (const float*)d_in[7];
    const float* Wi2 = (const float*)d_in[8];
    const float* bi2 = (const float*)d_in[9];
    const float* Wh2 = (const float*)d_in[10];
    const float* bh2 = (const float*)d_in[11];
    const float* Wo2 = (const float*)d_in[12];
    const float* bo2 = (const float*)d_in[13];
    const float* Wi3 = (const float*)d_in[14];
    const float* bi3 = (const float*)d_in[15];
    const float* Wh3 = (const float*)d_in[16];
    const float* bh3 = (const float*)d_in[17];
    const float* Wo3 = (const float*)d_in[18];
    const float* bo3 = (const float*)d_in[19];
    float* out = (float*)d_out;

    hipMemsetAsync(out, 0, (size_t)out_size * sizeof(float), stream);
    hipLaunchKernelGGL(hdmr_fused, dim3(NBLK), dim3(NT), 0, stream,
                       x, f0, Wi1, bi1, Wh1, bh1, Wo1, bo1,
                       Wi2, bi2, Wh2, bh2, Wo2, bo2,
                       Wi3, bi3, Wh3, bh3, Wo3, bo3, out);
}

// Round 4
// 264.834 us; speedup vs baseline: 1.3331x; 1.2790x over previous
//
#include <hip/hip_runtime.h>

#define HID 128
#define BM 128
#define NT 512
#define NTILE 64          // 8192 / BM
#define NNET 92
#define NBLK (NNET * NTILE)   // 5888, divisible by 8 -> bijective XCD swizzle

typedef _Float16 f16;
typedef _Float16 f16x2 __attribute__((ext_vector_type(2)));
typedef _Float16 f16x4 __attribute__((ext_vector_type(4)));
typedef _Float16 f16x8 __attribute__((ext_vector_type(8)));
typedef float f32x4 __attribute__((ext_vector_type(4)));

// variable indices per network: 8 singles, 28 pairs, 56 trips (lexicographic)
__constant__ signed char VARS_C[NNET][3] = {
  {0,-1,-1},{1,-1,-1},{2,-1,-1},{3,-1,-1},{4,-1,-1},{5,-1,-1},{6,-1,-1},{7,-1,-1},
  {0,1,-1},{0,2,-1},{0,3,-1},{0,4,-1},{0,5,-1},{0,6,-1},{0,7,-1},
  {1,2,-1},{1,3,-1},{1,4,-1},{1,5,-1},{1,6,-1},{1,7,-1},
  {2,3,-1},{2,4,-1},{2,5,-1},{2,6,-1},{2,7,-1},
  {3,4,-1},{3,5,-1},{3,6,-1},{3,7,-1},
  {4,5,-1},{4,6,-1},{4,7,-1},
  {5,6,-1},{5,7,-1},
  {6,7,-1},
  {0,1,2},{0,1,3},{0,1,4},{0,1,5},{0,1,6},{0,1,7},
  {0,2,3},{0,2,4},{0,2,5},{0,2,6},{0,2,7},
  {0,3,4},{0,3,5},{0,3,6},{0,3,7},
  {0,4,5},{0,4,6},{0,4,7},
  {0,5,6},{0,5,7},
  {0,6,7},
  {1,2,3},{1,2,4},{1,2,5},{1,2,6},{1,2,7},
  {1,3,4},{1,3,5},{1,3,6},{1,3,7},
  {1,4,5},{1,4,6},{1,4,7},
  {1,5,6},{1,5,7},
  {1,6,7},
  {2,3,4},{2,3,5},{2,3,6},{2,3,7},
  {2,4,5},{2,4,6},{2,4,7},
  {2,5,6},{2,5,7},
  {2,6,7},
  {3,4,5},{3,4,6},{3,4,7},
  {3,5,6},{3,5,7},
  {3,6,7},
  {4,5,6},{4,5,7},
  {4,6,7},
  {5,6,7}
};

// final = -35*f0 + sum_n COEF[n] * g_n   (derived from the HDMR recursion,
// including the reference's f_jj[variable-index] quirk in the trip term)
__constant__ float COEF_C[NNET] = {
  120.f, 15.f, 15.f, -6.f, -6.f, -6.f, -6.f, -6.f,
  -20.f,-20.f,-20.f,-20.f,-20.f,-20.f,-20.f,-20.f,
  1.f,1.f,1.f,1.f,1.f,1.f,1.f,1.f,1.f,1.f,
  1.f,1.f,1.f,1.f,1.f,1.f,1.f,1.f,1.f,1.f,
  1.f,1.f,1.f,1.f,1.f,1.f,1.f,1.f,1.f,1.f,
  1.f,1.f,1.f,1.f,1.f,1.f,1.f,1.f,1.f,1.f,
  1.f,1.f,1.f,1.f,1.f,1.f,1.f,1.f,1.f,1.f,
  1.f,1.f,1.f,1.f,1.f,1.f,1.f,1.f,1.f,1.f,
  1.f,1.f,1.f,1.f,1.f,1.f,1.f,1.f,1.f,1.f,
  1.f,1.f
};

__device__ __forceinline__ float fsigmoid(float v) {
    return __builtin_amdgcn_rcpf(1.0f + __expf(-v));
}

// XOR-swizzled byte offset into a [row][128] f16 tile (row stride 256 B).
__device__ __forceinline__ int actoff(int row, int colbyte) {
    return row * 256 + (colbyte ^ ((row & 7) << 4));
}

// ---- pre-pass: convert all W_h (fp32) -> f16 into workspace ----
// layout: [net 0..91][layer 0..1][jout 128][k 128], flat f16
#define S1 262144   // 8  * 2*128*128
#define S2 917504   // 28 * 2*128*128
#define S3 1835008  // 56 * 2*128*128
__global__ __launch_bounds__(256)
void cvt_wh(const float* __restrict__ Wh1, const float* __restrict__ Wh2,
            const float* __restrict__ Wh3, f16* __restrict__ dst) {
    const int i = (blockIdx.x * 256 + threadIdx.x) * 4;   // group sizes are %4==0
    if (i >= S1 + S2 + S3) return;
    const float* s;
    if (i < S1)            s = Wh1 + i;
    else if (i < S1 + S2)  s = Wh2 + (i - S1);
    else                   s = Wh3 + (i - S1 - S2);
    float4 v = *(const float4*)s;
    f16x4 h = { (f16)v.x, (f16)v.y, (f16)v.z, (f16)v.w };
    *(f16x4*)(dst + i) = h;
}

__global__ __launch_bounds__(NT, 4)   // <=128 VGPR, 2 blocks/CU (LDS-bound)
void hdmr_fused(const float* __restrict__ x, const float* __restrict__ f0p,
    const float* __restrict__ Wi1, const float* __restrict__ bi1,
    const float* __restrict__ bh1, const float* __restrict__ Wo1, const float* __restrict__ bo1,
    const float* __restrict__ Wi2, const float* __restrict__ bi2,
    const float* __restrict__ bh2, const float* __restrict__ Wo2, const float* __restrict__ bo2,
    const float* __restrict__ Wi3, const float* __restrict__ bi3,
    const float* __restrict__ bh3, const float* __restrict__ Wo3, const float* __restrict__ bo3,
    const f16* __restrict__ Whf, float* __restrict__ out)
{
    __shared__ __attribute__((aligned(16))) char actb[2][BM * HID * 2]; // 2x32KB ping-pong
    __shared__ float xs[BM][3];
    __shared__ float wout_s[HID];

    const int tid = threadIdx.x;
    const int bid = blockIdx.x;
    // bijective XCD-contiguous swizzle: same-network tiles stay on one XCD
    const int swz = (bid & 7) * (NBLK / 8) + (bid >> 3);
    const int N = swz >> 6;            // network id 0..91
    const int tile = swz & (NTILE - 1);
    const int m0 = tile * BM;

    int din, lidx;
    const float *Wi, *bi, *bh, *Wo, *bo;
    if (N < 8)       { lidx = N;      din = 1; Wi=Wi1; bi=bi1; bh=bh1; Wo=Wo1; bo=bo1; }
    else if (N < 36) { lidx = N - 8;  din = 2; Wi=Wi2; bi=bi2; bh=bh2; Wo=Wo2; bo=bo2; }
    else             { lidx = N - 36; din = 3; Wi=Wi3; bi=bi3; bh=bh3; Wo=Wo3; bo=bo3; }
    Wi += (size_t)lidx * HID * din;
    bi += (size_t)lidx * HID;
    bh += (size_t)lidx * 2 * HID;
    Wo += (size_t)lidx * HID;
    const float bout = bo[lidx];
    const f16* WN = Whf + (size_t)N * (2 * HID * HID);

    const int wv = tid >> 6;
    const int lane = tid & 63;
    const int lr = lane & 15;
    const int lk = lane >> 4;          // 0..3
    const int R0 = (wv >> 2) * 64;     // 64 batch rows (m) per wave
    const int C0 = (wv & 3) * 32;      // 32 hidden units (j) per wave

    // ---- prefetch layer-0 A-fragments (weights); latency hides under staging+input layer ----
    // A-frag (16x16x32): lane holds A[j = lane&15][k = (lane>>4)*8 .. +8]
    f16x8 wA0[2][4];
    #pragma unroll
    for (int jt = 0; jt < 2; ++jt)
        #pragma unroll
        for (int kt = 0; kt < 4; ++kt)
            wA0[jt][kt] = *(const f16x8*)(WN + (size_t)(C0 + jt * 16 + lr) * HID + kt * 32 + lk * 8);

    const int v0 = VARS_C[N][0], v1 = VARS_C[N][1], v2 = VARS_C[N][2];

    // ---- stage x slice + W_out ----
    if (tid < BM) {
        const float* xr = x + (size_t)(m0 + tid) * 8;
        xs[tid][0] = xr[v0];
        if (din > 1) xs[tid][1] = xr[v1];
        if (din > 2) xs[tid][2] = xr[v2];
    }
    if (tid >= NT - HID) wout_s[tid - (NT - HID)] = Wo[tid - (NT - HID)];
    __syncthreads();

    // ---- input layer (fp32 VALU), 2 cols/thread -> act0, layout [m][j] ----
    {
        const int j = (tid & 63) * 2;
        const float wA = Wi[j * din],     wAa = (din > 1) ? Wi[j * din + 1] : 0.f,
                    wAb = (din > 2) ? Wi[j * din + 2] : 0.f;
        const float wB = Wi[(j+1) * din], wBa = (din > 1) ? Wi[(j+1) * din + 1] : 0.f,
                    wBb = (din > 2) ? Wi[(j+1) * din + 2] : 0.f;
        const float bA = bi[j], bB = bi[j+1];
        for (int mm = (tid >> 6); mm < BM; mm += NT / 64) {
            float x0 = xs[mm][0];
            float sA = bA + x0 * wA, sB = bB + x0 * wB;
            if (din > 1) { float x1 = xs[mm][1]; sA += x1 * wAa; sB += x1 * wBa; }
            if (din > 2) { float x2 = xs[mm][2]; sA += x2 * wAb; sB += x2 * wBb; }
            f16x2 hv = { (f16)fsigmoid(sA), (f16)fsigmoid(sB) };
            *(f16x2*)(actb[0] + actoff(mm, j * 2)) = hv;
        }
    }
    __syncthreads();

    f16x8 wA1[2][4];
    f32x4 acc[2][4];

    // ================= hidden layer 0 =================
    #pragma unroll
    for (int jt = 0; jt < 2; ++jt)
        #pragma unroll
        for (int mt = 0; mt < 4; ++mt) acc[jt][mt] = (f32x4){0.f,0.f,0.f,0.f};
    #pragma unroll
    for (int kt = 0; kt < 4; ++kt) {
        // B-frag: lane holds B[k = (lane>>4)*8 .. +8][m = lane&15] = act[m][k...]
        f16x8 bfr[4];
        #pragma unroll
        for (int mt = 0; mt < 4; ++mt)
            bfr[mt] = *(const f16x8*)(actb[0] + actoff(R0 + mt * 16 + lr, (kt * 32 + lk * 8) * 2));
        #pragma unroll
        for (int jt = 0; jt < 2; ++jt)
            #pragma unroll
            for (int mt = 0; mt < 4; ++mt)
                acc[jt][mt] = __builtin_amdgcn_mfma_f32_16x16x32_f16(wA0[jt][kt], bfr[mt], acc[jt][mt], 0, 0, 0);
    }
    // prefetch layer-1 A-fragments; latency hides under sigmoid epilogue below
    #pragma unroll
    for (int jt = 0; jt < 2; ++jt)
        #pragma unroll
        for (int kt = 0; kt < 4; ++kt)
            wA1[jt][kt] = *(const f16x8*)(WN + HID * HID + (size_t)(C0 + jt * 16 + lr) * HID + kt * 32 + lk * 8);
    {
        // D layout: lane holds D[j = C0 + jt*16 + lk*4 + i][m = R0 + mt*16 + lr]
        f32x4 bc0 = *(const f32x4*)(bh + C0 + lk * 4);
        f32x4 bc1 = *(const f32x4*)(bh + C0 + 16 + lk * 4);
        #pragma unroll
        for (int jt = 0; jt < 2; ++jt) {
            #pragma unroll
            for (int mt = 0; mt < 4; ++mt) {
                f16x4 hv;
                #pragma unroll
                for (int i = 0; i < 4; ++i)
                    hv[i] = (f16)fsigmoid(acc[jt][mt][i] + (jt ? bc1[i] : bc0[i]));
                *(f16x4*)(actb[1] + actoff(R0 + mt * 16 + lr, (C0 + jt * 16 + lk * 4) * 2)) = hv;
            }
        }
    }
    __syncthreads();

    // ================= hidden layer 1 =================
    #pragma unroll
    for (int jt = 0; jt < 2; ++jt)
        #pragma unroll
        for (int mt = 0; mt < 4; ++mt) acc[jt][mt] = (f32x4){0.f,0.f,0.f,0.f};
    #pragma unroll
    for (int kt = 0; kt < 4; ++kt) {
        f16x8 bfr[4];
        #pragma unroll
        for (int mt = 0; mt < 4; ++mt)
            bfr[mt] = *(const f16x8*)(actb[1] + actoff(R0 + mt * 16 + lr, (kt * 32 + lk * 8) * 2));
        #pragma unroll
        for (int jt = 0; jt < 2; ++jt)
            #pragma unroll
            for (int mt = 0; mt < 4; ++mt)
                acc[jt][mt] = __builtin_amdgcn_mfma_f32_16x16x32_f16(wA1[jt][kt], bfr[mt], acc[jt][mt], 0, 0, 0);
    }
    {
        f32x4 bc0 = *(const f32x4*)(bh + HID + C0 + lk * 4);
        f32x4 bc1 = *(const f32x4*)(bh + HID + C0 + 16 + lk * 4);
        #pragma unroll
        for (int jt = 0; jt < 2; ++jt) {
            #pragma unroll
            for (int mt = 0; mt < 4; ++mt) {
                f16x4 hv;
                #pragma unroll
                for (int i = 0; i < 4; ++i)
                    hv[i] = (f16)fsigmoid(acc[jt][mt][i] + (jt ? bc1[i] : bc0[i]));
                *(f16x4*)(actb[0] + actoff(R0 + mt * 16 + lr, (C0 + jt * 16 + lk * 4) * 2)) = hv;
            }
        }
    }
    __syncthreads();

    // ---- output layer + HDMR combine (act in buffer 0) ----
    {
        const int row = tid >> 2;
        const int seg = tid & 3;
        float s = 0.0f;
        #pragma unroll
        for (int jj = 0; jj < 4; ++jj) {
            const int col = seg * 32 + jj * 8;
            f16x8 v = *(const f16x8*)(actb[0] + actoff(row, col * 2));
            #pragma unroll
            for (int k = 0; k < 8; ++k) s += (float)v[k] * wout_s[col + k];
        }
        s += __shfl_xor(s, 1);
        s += __shfl_xor(s, 2);
        if (seg == 0) {
            float y = s + bout;
            float val = COEF_C[N] * y;
            if (N == 0) val -= 35.0f * f0p[0];   // f0 term added exactly once per row
            atomicAdd(&out[m0 + row], val);
        }
    }
}

extern "C" void kernel_launch(void* const* d_in, const int* in_sizes, int n_in,
                              void* d_out, int out_size, void* d_ws, size_t ws_size,
                              hipStream_t stream) {
    const float* x   = (const float*)d_in[0];
    const float* f0  = (const float*)d_in[1];
    const float* Wi1 = (const float*)d_in[2];
    const float* bi1 = (const float*)d_in[3];
    const float* Wh1 = (const float*)d_in[4];
    const float* bh1 = (const float*)d_in[5];
    const float* Wo1 = (const float*)d_in[6];
    const float* bo1 = (const float*)d_in[7];
    const float* Wi2 = (const float*)d_in[8];
    const float* bi2 = (const float*)d_in[9];
    const float* Wh2 = (const float*)d_in[10];
    const float* bh2 = (const float*)d_in[11];
    const float* Wo2 = (const float*)d_in[12];
    const float* bo2 = (const float*)d_in[13];
    const float* Wi3 = (const float*)d_in[14];
    const float* bi3 = (const float*)d_in[15];
    const float* Wh3 = (const float*)d_in[16];
    const float* bh3 = (const float*)d_in[17];
    const float* Wo3 = (const float*)d_in[18];
    const float* bo3 = (const float*)d_in[19];
    float* out = (float*)d_out;
    f16* Whf = (f16*)d_ws;   // needs 3,014,656 * 2 B ≈ 5.8 MB

    hipMemsetAsync(out, 0, (size_t)out_size * sizeof(float), stream);
    hipLaunchKernelGGL(cvt_wh, dim3((S1 + S2 + S3) / 1024), dim3(256), 0, stream,
                       Wh1, Wh2, Wh3, Whf);
    hipLaunchKernelGGL(hdmr_fused, dim3(NBLK), dim3(NT), 0, stream,
                       x, f0, Wi1, bi1, bh1, Wo1, bo1,
                       Wi2, bi2, bh2, Wo2, bo2,
                       Wi3, bi3, bh3, Wo3, bo3, Whf, out);
}

// Round 5
// 228.909 us; speedup vs baseline: 1.5423x; 1.1569x over previous
//
#include <hip/hip_runtime.h>

#define HID 128
#define BM 128
#define NT 512
#define TPB 4                 // row-tiles per block
#define GRPS 16               // 8192 / (TPB*BM)
#define NNET 92
#define NBLK (NNET * GRPS)    // 1472, %8==0 -> bijective XCD swizzle
#define LOG2E 1.44269504f

typedef _Float16 f16;
typedef _Float16 f16x2 __attribute__((ext_vector_type(2)));
typedef _Float16 f16x4 __attribute__((ext_vector_type(4)));
typedef _Float16 f16x8 __attribute__((ext_vector_type(8)));
typedef float f32x4 __attribute__((ext_vector_type(4)));

// variable indices per network: 8 singles, 28 pairs, 56 trips (lexicographic)
__constant__ signed char VARS_C[NNET][3] = {
  {0,-1,-1},{1,-1,-1},{2,-1,-1},{3,-1,-1},{4,-1,-1},{5,-1,-1},{6,-1,-1},{7,-1,-1},
  {0,1,-1},{0,2,-1},{0,3,-1},{0,4,-1},{0,5,-1},{0,6,-1},{0,7,-1},
  {1,2,-1},{1,3,-1},{1,4,-1},{1,5,-1},{1,6,-1},{1,7,-1},
  {2,3,-1},{2,4,-1},{2,5,-1},{2,6,-1},{2,7,-1},
  {3,4,-1},{3,5,-1},{3,6,-1},{3,7,-1},
  {4,5,-1},{4,6,-1},{4,7,-1},
  {5,6,-1},{5,7,-1},
  {6,7,-1},
  {0,1,2},{0,1,3},{0,1,4},{0,1,5},{0,1,6},{0,1,7},
  {0,2,3},{0,2,4},{0,2,5},{0,2,6},{0,2,7},
  {0,3,4},{0,3,5},{0,3,6},{0,3,7},
  {0,4,5},{0,4,6},{0,4,7},
  {0,5,6},{0,5,7},
  {0,6,7},
  {1,2,3},{1,2,4},{1,2,5},{1,2,6},{1,2,7},
  {1,3,4},{1,3,5},{1,3,6},{1,3,7},
  {1,4,5},{1,4,6},{1,4,7},
  {1,5,6},{1,5,7},
  {1,6,7},
  {2,3,4},{2,3,5},{2,3,6},{2,3,7},
  {2,4,5},{2,4,6},{2,4,7},
  {2,5,6},{2,5,7},
  {2,6,7},
  {3,4,5},{3,4,6},{3,4,7},
  {3,5,6},{3,5,7},
  {3,6,7},
  {4,5,6},{4,5,7},
  {4,6,7},
  {5,6,7}
};

// final = -35*f0 + sum_n COEF[n] * g_n
__constant__ float COEF_C[NNET] = {
  120.f, 15.f, 15.f, -6.f, -6.f, -6.f, -6.f, -6.f,
  -20.f,-20.f,-20.f,-20.f,-20.f,-20.f,-20.f,-20.f,
  1.f,1.f,1.f,1.f,1.f,1.f,1.f,1.f,1.f,1.f,
  1.f,1.f,1.f,1.f,1.f,1.f,1.f,1.f,1.f,1.f,
  1.f,1.f,1.f,1.f,1.f,1.f,1.f,1.f,1.f,1.f,
  1.f,1.f,1.f,1.f,1.f,1.f,1.f,1.f,1.f,1.f,
  1.f,1.f,1.f,1.f,1.f,1.f,1.f,1.f,1.f,1.f,
  1.f,1.f,1.f,1.f,1.f,1.f,1.f,1.f,1.f,1.f,
  1.f,1.f,1.f,1.f,1.f,1.f,1.f,1.f,1.f,1.f,
  1.f,1.f
};

// s is already -log2e * (pre-activation)  ->  sigmoid = 1/(1+2^s)
__device__ __forceinline__ float sig2(float s) {
    return __builtin_amdgcn_rcpf(1.0f + __builtin_amdgcn_exp2f(s));
}

// XOR-swizzled byte offset into a [row][128] f16 tile (row stride 256 B).
__device__ __forceinline__ int actoff(int row, int colbyte) {
    return row * 256 + (colbyte ^ ((row & 7) << 4));
}

// ---- pre-pass: W_h scaled by -log2e -> f16; W_out -> f16 (unscaled) ----
#define SW 3014656          // 92 * 2*128*128
#define SO1 1024            // 8*128
#define SO2 3584            // 28*128
#define SO3 7168            // 56*128
#define CVT_TOTAL (SW + SO1 + SO2 + SO3)
__global__ __launch_bounds__(256)
void cvt_w(const float* __restrict__ Wh1, const float* __restrict__ Wh2,
           const float* __restrict__ Wh3, const float* __restrict__ Wo1,
           const float* __restrict__ Wo2, const float* __restrict__ Wo3,
           f16* __restrict__ dst) {
    const int i = (blockIdx.x * 256 + threadIdx.x) * 4;
    if (i >= CVT_TOTAL) return;
    float scale;
    const float* s;
    if (i < SW) {           // hidden weights, scaled (group sizes all %4==0)
        scale = -LOG2E;
        if (i < 262144)         s = Wh1 + i;
        else if (i < 1179648)   s = Wh2 + (i - 262144);
        else                    s = Wh3 + (i - 1179648);
    } else {                // output weights, unscaled
        scale = 1.0f;
        int j = i - SW;
        if (j < SO1)            s = Wo1 + j;
        else if (j < SO1 + SO2) s = Wo2 + (j - SO1);
        else                    s = Wo3 + (j - SO1 - SO2);
    }
    float4 v = *(const float4*)s;
    f16x4 h = { (f16)(scale*v.x), (f16)(scale*v.y), (f16)(scale*v.z), (f16)(scale*v.w) };
    *(f16x4*)(dst + i) = h;
}

__global__ __launch_bounds__(NT, 4)   // <=128 VGPR -> 2 blocks/CU (LDS-bound)
void hdmr_fused(const float* __restrict__ x, const float* __restrict__ f0p,
    const float* __restrict__ Wi1, const float* __restrict__ bi1,
    const float* __restrict__ bh1, const float* __restrict__ bo1,
    const float* __restrict__ Wi2, const float* __restrict__ bi2,
    const float* __restrict__ bh2, const float* __restrict__ bo2,
    const float* __restrict__ Wi3, const float* __restrict__ bi3,
    const float* __restrict__ bh3, const float* __restrict__ bo3,
    const f16* __restrict__ Whf, const f16* __restrict__ WoF,
    float* __restrict__ out)
{
    __shared__ __attribute__((aligned(16))) char actb[2][BM * HID * 2]; // 64KB ping-pong
    __shared__ __attribute__((aligned(16))) float xr[2][BM * 8];        // 8KB raw x tiles
    __shared__ float wi_s[HID][3];
    __shared__ float bi_s[HID];

    const int tid = threadIdx.x;
    const int bid = blockIdx.x;
    const int swz = (bid & 7) * (NBLK / 8) + (bid >> 3);   // bijective XCD swizzle
    const int N = swz >> 4;            // network id 0..91
    const int grp = swz & (GRPS - 1);
    const int m_base = grp * (TPB * BM);

    int din, lidx;
    const float *Wi, *bi, *bh, *bo;
    if (N < 8)       { lidx = N;      din = 1; Wi=Wi1; bi=bi1; bh=bh1; bo=bo1; }
    else if (N < 36) { lidx = N - 8;  din = 2; Wi=Wi2; bi=bi2; bh=bh2; bo=bo2; }
    else             { lidx = N - 36; din = 3; Wi=Wi3; bi=bi3; bh=bh3; bo=bo3; }
    Wi += (size_t)lidx * HID * din;
    bi += (size_t)lidx * HID;
    bh += (size_t)lidx * 2 * HID;
    const float bout = bo[lidx];
    const float coef = COEF_C[N];
    const float f0c = (N == 0) ? 35.0f * f0p[0] : 0.0f;
    const f16* WN = Whf + (size_t)N * (2 * HID * HID);

    const int lane = tid & 63;
    const int wv = tid >> 6;           // 8 waves
    const int lr = lane & 15;
    const int lk = lane >> 4;          // 0..3
    const int C0 = wv * 16;            // this wave's 16-col (j) slice; also its 16-row band

    // ---- permanent register state: weights for both layers + output, biases ----
    f16x8 wA0[4], wA1[4], wOut[4];
    #pragma unroll
    for (int kt = 0; kt < 4; ++kt) {
        wA0[kt] = *(const f16x8*)(WN + (size_t)(C0 + lr) * HID + kt * 32 + lk * 8);
        wA1[kt] = *(const f16x8*)(WN + HID * HID + (size_t)(C0 + lr) * HID + kt * 32 + lk * 8);
        wOut[kt] = *(const f16x8*)(WoF + (size_t)N * HID + kt * 32 + lk * 8);
    }
    f32x4 bias0 = *(const f32x4*)(bh + C0 + lk * 4);
    f32x4 bias1 = *(const f32x4*)(bh + HID + C0 + lk * 4);
    #pragma unroll
    for (int i = 0; i < 4; ++i) { bias0[i] *= -LOG2E; bias1[i] *= -LOG2E; }

    const int v0 = VARS_C[N][0];
    const int v1 = VARS_C[N][1] < 0 ? 0 : VARS_C[N][1];
    const int v2 = VARS_C[N][2] < 0 ? 0 : VARS_C[N][2];

    // ---- stage input-layer weights (scaled, zero-padded) + first x tile ----
    if (tid < HID) {
        #pragma unroll
        for (int ii = 0; ii < 3; ++ii)
            wi_s[tid][ii] = (ii < din) ? -LOG2E * Wi[tid * din + ii] : 0.0f;
        bi_s[tid] = -LOG2E * bi[tid];
    }
    if (tid < 256)
        ((float4*)xr[0])[tid] = ((const float4*)(x + (size_t)m_base * 8))[tid];
    __syncthreads();

    f32x4 acc[8];

    for (int t = 0; t < TPB; ++t) {
        const int p = t & 1;
        // ======== phase A: output MFMA for tile t-1 (buf p^1) + input layer t (buf p) ========
        f32x4 acco = (f32x4){0.f, 0.f, 0.f, 0.f};
        if (t > 0) {
            #pragma unroll
            for (int kt = 0; kt < 4; ++kt) {
                f16x8 bfr = *(const f16x8*)(actb[p ^ 1] + actoff(C0 + lr, (kt * 32 + lk * 8) * 2));
                acco = __builtin_amdgcn_mfma_f32_16x16x32_f16(wOut[kt], bfr, acco, 0, 0, 0);
            }
        }
        {   // input layer: this wave's 16-row band, lane covers row C0+lr, cols lk*32..+32
            const int r = C0 + lr;
            const float* xrow = &xr[p][r * 8];
            const float x0 = xrow[v0], x1 = xrow[v1], x2 = xrow[v2];
            #pragma unroll
            for (int q = 0; q < 16; ++q) {
                const int c = lk * 32 + q * 2;
                float sA = bi_s[c]     + x0 * wi_s[c][0]     + x1 * wi_s[c][1]     + x2 * wi_s[c][2];
                float sB = bi_s[c + 1] + x0 * wi_s[c + 1][0] + x1 * wi_s[c + 1][1] + x2 * wi_s[c + 1][2];
                f16x2 hv = { (f16)sig2(sA), (f16)sig2(sB) };
                *(f16x2*)(actb[p] + actoff(r, c * 2)) = hv;
            }
        }
        if (t > 0 && lk == 0) {
            // D[j][m]: wout replicated over j -> every lane holds out[m=lr]; lanes lk==0 commit
            atomicAdd(&out[m_base + (t - 1) * BM + C0 + lr], coef * (acco[0] + bout) - f0c);
        }
        __syncthreads();

        // ======== hidden layer 0: buf p -> buf p^1 ========
        #pragma unroll
        for (int mt = 0; mt < 8; ++mt) acc[mt] = bias0;
        #pragma unroll
        for (int kt = 0; kt < 4; ++kt) {
            const int kb = (kt * 32 + lk * 8) * 2;
            #pragma unroll
            for (int mh = 0; mh < 2; ++mh) {   // halves to limit live bfr regs
                f16x8 bfr[4];
                #pragma unroll
                for (int mi = 0; mi < 4; ++mi)
                    bfr[mi] = *(const f16x8*)(actb[p] + actoff((mh * 4 + mi) * 16 + lr, kb));
                #pragma unroll
                for (int mi = 0; mi < 4; ++mi)
                    acc[mh * 4 + mi] = __builtin_amdgcn_mfma_f32_16x16x32_f16(wA0[kt], bfr[mi], acc[mh * 4 + mi], 0, 0, 0);
            }
        }
        // prefetch next x tile (waves 0-3) while MFMAs drain
        if (t + 1 < TPB && tid < 256)
            ((float4*)xr[p ^ 1])[tid] = ((const float4*)(x + (size_t)(m_base + (t + 1) * BM) * 8))[tid];
        #pragma unroll
        for (int mt = 0; mt < 8; ++mt) {
            f16x4 hv;
            #pragma unroll
            for (int i = 0; i < 4; ++i) hv[i] = (f16)sig2(acc[mt][i]);
            *(f16x4*)(actb[p ^ 1] + actoff(mt * 16 + lr, (C0 + lk * 4) * 2)) = hv;
        }
        __syncthreads();

        // ======== hidden layer 1: buf p^1 -> buf p ========
        #pragma unroll
        for (int mt = 0; mt < 8; ++mt) acc[mt] = bias1;
        #pragma unroll
        for (int kt = 0; kt < 4; ++kt) {
            const int kb = (kt * 32 + lk * 8) * 2;
            #pragma unroll
            for (int mh = 0; mh < 2; ++mh) {
                f16x8 bfr[4];
                #pragma unroll
                for (int mi = 0; mi < 4; ++mi)
                    bfr[mi] = *(const f16x8*)(actb[p ^ 1] + actoff((mh * 4 + mi) * 16 + lr, kb));
                #pragma unroll
                for (int mi = 0; mi < 4; ++mi)
                    acc[mh * 4 + mi] = __builtin_amdgcn_mfma_f32_16x16x32_f16(wA1[kt], bfr[mi], acc[mh * 4 + mi], 0, 0, 0);
            }
        }
        #pragma unroll
        for (int mt = 0; mt < 8; ++mt) {
            f16x4 hv;
            #pragma unroll
            for (int i = 0; i < 4; ++i) hv[i] = (f16)sig2(acc[mt][i]);
            *(f16x4*)(actb[p] + actoff(mt * 16 + lr, (C0 + lk * 4) * 2)) = hv;
        }
        __syncthreads();
    }

    // ======== final output for tile TPB-1 (act in buf[(TPB-1)&1] = buf 1) ========
    {
        f32x4 acco = (f32x4){0.f, 0.f, 0.f, 0.f};
        #pragma unroll
        for (int kt = 0; kt < 4; ++kt) {
            f16x8 bfr = *(const f16x8*)(actb[1] + actoff(C0 + lr, (kt * 32 + lk * 8) * 2));
            acco = __builtin_amdgcn_mfma_f32_16x16x32_f16(wOut[kt], bfr, acco, 0, 0, 0);
        }
        if (lk == 0)
            atomicAdd(&out[m_base + (TPB - 1) * BM + C0 + lr], coef * (acco[0] + bout) - f0c);
    }
}

extern "C" void kernel_launch(void* const* d_in, const int* in_sizes, int n_in,
                              void* d_out, int out_size, void* d_ws, size_t ws_size,
                              hipStream_t stream) {
    const float* x   = (const float*)d_in[0];
    const float* f0  = (const float*)d_in[1];
    const float* Wi1 = (const float*)d_in[2];
    const float* bi1 = (const float*)d_in[3];
    const float* Wh1 = (const float*)d_in[4];
    const float* bh1 = (const float*)d_in[5];
    const float* Wo1 = (const float*)d_in[6];
    const float* bo1 = (const float*)d_in[7];
    const float* Wi2 = (const float*)d_in[8];
    const float* bi2 = (const float*)d_in[9];
    const float* Wh2 = (const float*)d_in[10];
    const float* bh2 = (const float*)d_in[11];
    const float* Wo2 = (const float*)d_in[12];
    const float* bo2 = (const float*)d_in[13];
    const float* Wi3 = (const float*)d_in[14];
    const float* bi3 = (const float*)d_in[15];
    const float* Wh3 = (const float*)d_in[16];
    const float* bh3 = (const float*)d_in[17];
    const float* Wo3 = (const float*)d_in[18];
    const float* bo3 = (const float*)d_in[19];
    float* out = (float*)d_out;
    f16* Whf = (f16*)d_ws;                 // ~5.8 MB scaled hidden weights
    f16* WoF = Whf + SW;                   // +23 KB output weights

    hipMemsetAsync(out, 0, (size_t)out_size * sizeof(float), stream);
    hipLaunchKernelGGL(cvt_w, dim3((CVT_TOTAL / 4 + 255) / 256), dim3(256), 0, stream,
                       Wh1, Wh2, Wh3, Wo1, Wo2, Wo3, Whf);
    hipLaunchKernelGGL(hdmr_fused, dim3(NBLK), dim3(NT), 0, stream,
                       x, f0, Wi1, bi1, bh1, bo1,
                       Wi2, bi2, bh2, bo2,
                       Wi3, bi3, bh3, bo3, Whf, WoF, out);
}